// Round 3
// baseline (289.686 us; speedup 1.0000x reference)
//
#include <hip/hip_runtime.h>
#include <hip/hip_bf16.h>

#define B_  4
#define C_  256
#define C8_ 32
#define N_  16384

typedef unsigned short ushort_t;
typedef __attribute__((ext_vector_type(8))) short short8;
typedef __attribute__((ext_vector_type(4))) float floatx4;

__device__ __forceinline__ short bf16_rne(float f) {
  unsigned u = __float_as_uint(f);
  u += 0x7fffu + ((u >> 16) & 1u);
  return (short)(u >> 16);
}

__device__ __forceinline__ short8 pack8(float f0, float f1, float f2, float f3,
                                        float f4, float f5, float f6, float f7) {
  union { short8 s; __hip_bfloat162 h[4]; } u;
  u.h[0] = __float22bfloat162_rn(make_float2(f0, f1));
  u.h[1] = __float22bfloat162_rn(make_float2(f2, f3));
  u.h[2] = __float22bfloat162_rn(make_float2(f4, f5));
  u.h[3] = __float22bfloat162_rn(make_float2(f6, f7));
  return u.s;
}

// K0: zero den; cast Wk -> bf16. grid 32 x 256.
__global__ __launch_bounds__(256) void k0_init(const float* __restrict__ Wk,
                                               ushort_t* __restrict__ Wkb,
                                               float* __restrict__ den) {
  const int i = blockIdx.x * 256 + threadIdx.x;
  Wkb[i] = (ushort_t)bf16_rne(Wk[i]);
  if (i < 128) den[i] = 0.f;
}

// KT: x[b][c][n] fp32 -> xT[b][n][c] bf16, 64x64 LDS tiles.
// grid 4096 = B * 4(c/64) * 256(n/64), block 256.
__global__ __launch_bounds__(256) void kT_transpose(const float* __restrict__ x,
                                                    ushort_t* __restrict__ xT) {
  __shared__ ushort_t T[64 * 70];  // pad 70: c-jump of 16 rows lands on distinct banks
  const int t = threadIdx.x;
  const int b = blockIdx.x >> 10;
  const int c0 = ((blockIdx.x >> 8) & 3) * 64;
  const int n0 = (blockIdx.x & 255) * 64;
  const int r = t >> 2, q = t & 3;
  const float* xp = x + (size_t)(b * C_ + c0 + r) * N_ + n0 + q * 16;
  unsigned* Tw = (unsigned*)&T[r * 70 + q * 16];  // (r*70+q*16)*2 is 4B-aligned
#pragma unroll
  for (int i = 0; i < 4; ++i) {
    float4 v = *(const float4*)(xp + i * 4);
    __hip_bfloat162 h0 = __float22bfloat162_rn(make_float2(v.x, v.y));
    __hip_bfloat162 h1 = __float22bfloat162_rn(make_float2(v.z, v.w));
    Tw[i * 2 + 0] = *(unsigned*)&h0;
    Tw[i * 2 + 1] = *(unsigned*)&h1;
  }
  __syncthreads();
  const int n = t >> 2;  // local n row this thread emits
  unsigned u[8];
#pragma unroll
  for (int j = 0; j < 8; ++j) {
    unsigned lo = T[(q * 16 + 2 * j) * 70 + n];
    unsigned hi = T[(q * 16 + 2 * j + 1) * 70 + n];
    u[j] = lo | (hi << 16);
  }
  ushort_t* dst = xT + (size_t)(b * N_ + n0 + n) * C_ + c0 + q * 16;
  *(uint4*)(dst) = make_uint4(u[0], u[1], u[2], u[3]);
  *(uint4*)(dst + 8) = make_uint4(u[4], u[5], u[6], u[7]);
}

// K1: p = exp(Wk.x + bk) (no max-sub: |klog| < ~6), den += rowsum(p).
// A = Wkb (direct short8), B = xT rows (direct short8). grid B*128, block 4 waves.
__global__ __launch_bounds__(256) void k1_p(const ushort_t* __restrict__ xT,
                                            const ushort_t* __restrict__ Wkb,
                                            const float* __restrict__ bk,
                                            ushort_t* __restrict__ p,
                                            float* __restrict__ den) {
  const int t = threadIdx.x;
  const int lane = t & 63;
  const int w = t >> 6;
  const int b = blockIdx.x >> 7;
  const int n0 = (blockIdx.x & 127) * 128 + w * 32;
  const int l15 = lane & 15, l4 = lane >> 4;
  const floatx4 z = {0.f, 0.f, 0.f, 0.f};
  floatx4 acc[2][2];
  acc[0][0] = z; acc[0][1] = z; acc[1][0] = z; acc[1][1] = z;

  for (int kc = 0; kc < 8; ++kc) {
    const int kb = kc * 32 + l4 * 8;
    short8 a0 = *(const short8*)&Wkb[l15 * C_ + kb];
    short8 a1 = *(const short8*)&Wkb[(16 + l15) * C_ + kb];
#pragma unroll
    for (int nt = 0; nt < 2; ++nt) {
      short8 bf = *(const short8*)&xT[(size_t)(b * N_ + n0 + nt * 16 + l15) * C_ + kb];
      acc[0][nt] = __builtin_amdgcn_mfma_f32_16x16x32_bf16(a0, bf, acc[0][nt], 0, 0, 0);
      acc[1][nt] = __builtin_amdgcn_mfma_f32_16x16x32_bf16(a1, bf, acc[1][nt], 0, 0, 0);
    }
  }
#pragma unroll
  for (int mt = 0; mt < 2; ++mt) {
    float ds[4] = {0.f, 0.f, 0.f, 0.f};
#pragma unroll
    for (int nt = 0; nt < 2; ++nt) {
#pragma unroll
      for (int rg = 0; rg < 4; ++rg) {
        const int o = mt * 16 + l4 * 4 + rg;
        const int n = n0 + nt * 16 + l15;
        float pe = __expf(acc[mt][nt][rg] + bk[o]);
        p[(size_t)(b * C8_ + o) * N_ + n] = (ushort_t)bf16_rne(pe);
        ds[rg] += pe;
      }
    }
#pragma unroll
    for (int rg = 0; rg < 4; ++rg) {
      float s = ds[rg];
      s += __shfl_xor(s, 1); s += __shfl_xor(s, 2);
      s += __shfl_xor(s, 4); s += __shfl_xor(s, 8);
      if (l15 == 0) atomicAdd(&den[b * C8_ + mt * 16 + l4 * 4 + rg], s);
    }
  }
}

// K3: partials kxp[b][ch][c][o] = sum_{n in 128-chunk} x[c][n]*p[o][n].
// A = x (float4 + pack), B = p (direct short8). grid B*128, block 4 waves (wave = 64c x 32o).
__global__ __launch_bounds__(256) void k3_kxp(const float* __restrict__ x,
                                              const ushort_t* __restrict__ p,
                                              float* __restrict__ kxp) {
  const int t = threadIdx.x;
  const int lane = t & 63;
  const int w = t >> 6;
  const int b = blockIdx.x >> 7;
  const int ch = blockIdx.x & 127;
  const int c0 = w * 64;
  const int l15 = lane & 15, l4 = lane >> 4;
  const floatx4 z = {0.f, 0.f, 0.f, 0.f};
  floatx4 acc[4][2];
#pragma unroll
  for (int mt = 0; mt < 4; ++mt) { acc[mt][0] = z; acc[mt][1] = z; }

  for (int kc = 0; kc < 4; ++kc) {
    const int kn = ch * 128 + kc * 32 + l4 * 8;
    short8 b0 = *(const short8*)&p[(size_t)(b * C8_ + l15) * N_ + kn];
    short8 b1 = *(const short8*)&p[(size_t)(b * C8_ + 16 + l15) * N_ + kn];
#pragma unroll
    for (int mt = 0; mt < 4; ++mt) {
      const float* xp = x + (size_t)(b * C_ + c0 + mt * 16 + l15) * N_ + kn;
      float4 xa = *(const float4*)xp;
      float4 xb = *(const float4*)(xp + 4);
      short8 af = pack8(xa.x, xa.y, xa.z, xa.w, xb.x, xb.y, xb.z, xb.w);
      acc[mt][0] = __builtin_amdgcn_mfma_f32_16x16x32_bf16(af, b0, acc[mt][0], 0, 0, 0);
      acc[mt][1] = __builtin_amdgcn_mfma_f32_16x16x32_bf16(af, b1, acc[mt][1], 0, 0, 0);
    }
  }
  float* dst = kxp + (size_t)(b * 128 + ch) * (C_ * C8_);
#pragma unroll
  for (int mt = 0; mt < 4; ++mt)
#pragma unroll
    for (int ot = 0; ot < 2; ++ot)
#pragma unroll
      for (int rg = 0; rg < 4; ++rg) {
        const int c = c0 + mt * 16 + l4 * 4 + rg;
        const int o = ot * 16 + l15;
        dst[c * C8_ + o] = acc[mt][ot][rg];
      }
}

// K3b: kx[b][o][c] = (sum_ch kxp)/den. grid 128 = B*32 (8-c groups), block 256 = 8c x 32o.
__global__ __launch_bounds__(256) void k3b_reduce(const float* __restrict__ kxp,
                                                  const float* __restrict__ den,
                                                  float* __restrict__ kx) {
  const int t = threadIdx.x;
  const int b = blockIdx.x >> 5;
  const int c = (blockIdx.x & 31) * 8 + (t >> 5);
  const int o = t & 31;
  float s = 0.f;
  for (int ch = 0; ch < 128; ++ch)
    s += kxp[(size_t)(b * 128 + ch) * (C_ * C8_) + c * C8_ + o];
  kx[(size_t)(b * C8_ + o) * C_ + c] = s / den[b * C8_ + o];
}

// K4a: kv[b][o][c] = Wv[c][:].kx[b][o][:] + bv[c]. grid 128, thread = c.
__global__ __launch_bounds__(256) void k4a_kv(const float* __restrict__ Wv,
                                              const float* __restrict__ bv,
                                              const float* __restrict__ kx,
                                              float* __restrict__ kv) {
  __shared__ float kxl[C_];
  const int t = threadIdx.x;
  const int bo = blockIdx.x;
  kxl[t] = kx[(size_t)bo * C_ + t];
  __syncthreads();
  const float4* wr = (const float4*)&Wv[(size_t)t * C_];
  float s = 0.f;
#pragma unroll 8
  for (int c4 = 0; c4 < 64; ++c4) {
    float4 wv = wr[c4];
    float4 k4 = *(const float4*)&kxl[c4 * 4];
    s += wv.x * k4.x + wv.y * k4.y + wv.z * k4.z + wv.w * k4.w;
  }
  kv[(size_t)bo * C_ + t] = s + bv[t];
}

// K4b: Mt[b][c][c''] bf16 (transposed for K5's B operand); r[b][c]. grid 64, block 256.
__global__ __launch_bounds__(256) void k4b_M(const float* __restrict__ Wq,
                                             const float* __restrict__ bq,
                                             const float* __restrict__ kv,
                                             ushort_t* __restrict__ Mt,
                                             float* __restrict__ r) {
  __shared__ float kvl[C8_ * C_];
  __shared__ float wqT[16 * C8_];
  const int t = threadIdx.x;
  const int b = blockIdx.x >> 4;
  const int c0 = (blockIdx.x & 15) * 16;
  for (int s = 0; s < 32; ++s)
    kvl[s * 256 + t] = kv[(size_t)b * C8_ * C_ + s * 256 + t];
#pragma unroll
  for (int s = 0; s < 2; ++s) {
    int f = s * 256 + t;
    int o = f >> 4, i = f & 15;
    wqT[i * C8_ + o] = Wq[o * C_ + c0 + i];
  }
  __syncthreads();
  float kvreg[C8_];
#pragma unroll
  for (int o = 0; o < C8_; ++o) kvreg[o] = kvl[o * C_ + t];
  for (int i = 0; i < 16; ++i) {
    const float4* w4 = (const float4*)&wqT[i * C8_];
    float s = 0.f;
#pragma unroll
    for (int o8 = 0; o8 < 8; ++o8) {
      float4 wv = w4[o8];
      s += wv.x * kvreg[o8 * 4] + wv.y * kvreg[o8 * 4 + 1] +
           wv.z * kvreg[o8 * 4 + 2] + wv.w * kvreg[o8 * 4 + 3];
    }
    Mt[(size_t)(b * C_ + t) * C_ + c0 + i] = (ushort_t)bf16_rne(s);
  }
  if (c0 == 0) {
    float rr = 0.f;
#pragma unroll
    for (int o = 0; o < C8_; ++o) rr += bq[o] * kvreg[o];
    r[b * C_ + t] = rr;
  }
}

// K5: out[b][n][c] = gamma*(x^T.M + r) + x. A = xT rows, B = Mt rows (both direct short8).
// grid B*128 (n-tiles of 128), block 4 waves; wave = 32n x 256c, B-frag reused 2x.
__global__ __launch_bounds__(256) void k5_mfma(const float* __restrict__ x,
                                               const ushort_t* __restrict__ xT,
                                               const ushort_t* __restrict__ Mt,
                                               const float* __restrict__ r,
                                               const float* __restrict__ gamma_p,
                                               float* __restrict__ out) {
  const int t = threadIdx.x;
  const int lane = t & 63;
  const int w = t >> 6;
  const int b = blockIdx.x >> 7;
  const int n0 = (blockIdx.x & 127) * 128 + w * 32;
  const int l15 = lane & 15, l4 = lane >> 4;
  const floatx4 z = {0.f, 0.f, 0.f, 0.f};
  floatx4 acc[16][2];
#pragma unroll
  for (int ct = 0; ct < 16; ++ct) { acc[ct][0] = z; acc[ct][1] = z; }

  for (int kc = 0; kc < 8; ++kc) {
    const int kb = kc * 32 + l4 * 8;
    short8 a0 = *(const short8*)&xT[(size_t)(b * N_ + n0 + l15) * C_ + kb];
    short8 a1 = *(const short8*)&xT[(size_t)(b * N_ + n0 + 16 + l15) * C_ + kb];
#pragma unroll
    for (int ct = 0; ct < 16; ++ct) {
      short8 bf = *(const short8*)&Mt[(size_t)(b * C_ + ct * 16 + l15) * C_ + kb];
      acc[ct][0] = __builtin_amdgcn_mfma_f32_16x16x32_bf16(a0, bf, acc[ct][0], 0, 0, 0);
      acc[ct][1] = __builtin_amdgcn_mfma_f32_16x16x32_bf16(a1, bf, acc[ct][1], 0, 0, 0);
    }
  }
  const float g = gamma_p[0];
#pragma unroll
  for (int ct = 0; ct < 16; ++ct) {
    const int c = ct * 16 + l15;
    const float rv = r[b * C_ + c];
#pragma unroll
    for (int nt = 0; nt < 2; ++nt)
#pragma unroll
      for (int rg = 0; rg < 4; ++rg) {
        const int n = n0 + nt * 16 + l4 * 4 + rg;
        const size_t idx = ((size_t)b * N_ + n) * C_ + c;
        out[idx] = g * (acc[ct][nt][rg] + rv) + x[idx];
      }
  }
}

extern "C" void kernel_launch(void* const* d_in, const int* in_sizes, int n_in,
                              void* d_out, int out_size, void* d_ws, size_t ws_size,
                              hipStream_t stream) {
  const float* x  = (const float*)d_in[0];
  const float* Wq = (const float*)d_in[1];
  const float* bq = (const float*)d_in[2];
  const float* Wk = (const float*)d_in[3];
  const float* bk = (const float*)d_in[4];
  const float* Wv = (const float*)d_in[5];
  const float* bv = (const float*)d_in[6];
  const float* gm = (const float*)d_in[7];
  float* out = (float*)d_out;

  float* ws = (float*)d_ws;
  float*    den = ws;                                    // 128
  ushort_t* Wkb = (ushort_t*)(ws + 128);                 // 4096 fl
  ushort_t* xT  = (ushort_t*)(ws + 128 + 4096);          // B*N*C ushort = 8388608 fl
  ushort_t* p   = (ushort_t*)(ws + 128 + 4096 + 8388608);            // 1048576 fl
  float*    kxp = ws + 128 + 4096 + 8388608 + 1048576;               // 4194304 fl
  float*    kx  = kxp + 4194304;                         // 32768
  float*    kv  = kx + 32768;                            // 32768
  ushort_t* Mt  = (ushort_t*)(kv + 32768);               // 131072 fl
  float*    r   = (float*)(kv + 32768 + 131072);         // 1024

  k0_init     <<<32,   256, 0, stream>>>(Wk, Wkb, den);
  kT_transpose<<<4096, 256, 0, stream>>>(x, xT);
  k1_p        <<<512,  256, 0, stream>>>(xT, Wkb, bk, p, den);
  k3_kxp      <<<512,  256, 0, stream>>>(x, p, kxp);
  k3b_reduce  <<<128,  256, 0, stream>>>(kxp, den, kx);
  k4a_kv      <<<128,  256, 0, stream>>>(Wv, bv, kx, kv);
  k4b_M       <<<64,   256, 0, stream>>>(Wq, bq, kv, Mt, r);
  k5_mfma     <<<512,  256, 0, stream>>>(x, xT, Mt, r, gm, out);
}